// Round 1
// baseline (602.283 us; speedup 1.0000x reference)
//
#include <hip/hip_runtime.h>

// ---------- shapes ----------
#define B_TOT 8192
#define S86   86
#define SPAD  96
#define D64   64
#define NQKV  192
#define RPOOL 8      // 1 global + 7 regions
#define KOUT  512    // (1+R)*D
#define NOUT  128

using bf16x8 = __attribute__((ext_vector_type(8))) short;
using f32x4  = __attribute__((ext_vector_type(4))) float;

#define MFMA(a, b, c) __builtin_amdgcn_mfma_f32_16x16x32_bf16((a), (b), (c), 0, 0, 0)

__device__ inline unsigned short f2bf(float f) {
  unsigned int u = __float_as_uint(f);
  u += 0x7fff + ((u >> 16) & 1);          // RNE
  return (unsigned short)(u >> 16);
}
__device__ inline float bf2f(unsigned short h) {
  return __uint_as_float(((unsigned int)h) << 16);
}

// ---------- ws layout (bytes) ----------
#define OFF_SP    0          // 5504 f32  -> 22016
#define OFF_PW    22016      // 768 f32   -> 3072
#define OFF_WQKV  25088      // 12288 bf16-> 24576
#define OFF_WA    49664      // 4096 bf16 -> 8192
#define OFF_WO    57856      // 65536 bf16-> 131072
#define OFF_C     188928     // 8192*512 bf16 -> 8388608

// ============================================================ prologue
__global__ void prologue(const float* __restrict__ cstat, const float* __restrict__ Wc,
                         const float* __restrict__ bc, const float* __restrict__ Wqkv,
                         const float* __restrict__ Wa, const float* __restrict__ Wo,
                         float* __restrict__ sp, float* __restrict__ pw,
                         unsigned short* __restrict__ wqkv_t,
                         unsigned short* __restrict__ wa_t,
                         unsigned short* __restrict__ wo_t) {
  const int b = blockIdx.x, tid = threadIdx.x;
  if (b < 32) {                       // Wo (512,128) -> wo_t [128][512] bf16
    #pragma unroll
    for (int ii = 0; ii < 8; ++ii) {
      int idx = ii * 256 + tid;
      int kl = idx >> 7, n = idx & 127;
      int k = b * 16 + kl;
      wo_t[n * 512 + k] = f2bf(Wo[k * 128 + n]);
    }
  } else if (b == 32) {               // static part of token projection (f32)
    for (int i = tid; i < S86 * 64; i += 256) {
      int s = i >> 6, d = i & 63;
      float v = bc[d];
      #pragma unroll
      for (int f = 0; f < 11; ++f) v += cstat[s * 11 + f] * Wc[(2 + f) * 64 + d];
      sp[i] = v;
    }
  } else if (b == 33) {               // Wqkv (64,192) -> wqkv_t [192][64]
    for (int i = tid; i < 64 * 192; i += 256) {
      int k = i / 192, n = i % 192;
      wqkv_t[n * 64 + k] = f2bf(Wqkv[i]);
    }
  } else if (b == 34) {               // Wa (64,64) -> wa_t [64][64]
    for (int i = tid; i < 64 * 64; i += 256) {
      int k = i >> 6, n = i & 63;
      wa_t[n * 64 + k] = f2bf(Wa[i]);
    }
  } else {                            // pooling weights [8][96]
    __shared__ float cnt[7];
    if (tid < 7) {
      int c = 0;
      for (int s = 0; s < S86; ++s) c += (cstat[s * 11 + 2 + tid] > 0.5f) ? 1 : 0;
      cnt[tid] = 1.0f / (float)(c < 1 ? 1 : c);
    }
    __syncthreads();
    for (int i = tid; i < RPOOL * SPAD; i += 256) {
      int p = i / 96, s = i % 96;
      float v = 0.f;
      if (s < S86) {
        if (p == 0) v = 1.0f / 86.0f;
        else v = (cstat[s * 11 + 2 + (p - 1)] > 0.5f) ? cnt[p - 1] : 0.f;
      }
      pw[i] = v;
    }
  }
}

// ============================================================ fused per-batch kernel
__global__ __launch_bounds__(256, 2) void fused(
    const float* __restrict__ influence, const float* __restrict__ Wc,
    const float* __restrict__ bqkv, const float* __restrict__ ba,
    const float* __restrict__ sp, const float* __restrict__ pw,
    const unsigned short* __restrict__ wqkv_t, const unsigned short* __restrict__ wa_t,
    unsigned short* __restrict__ c_ws) {

  __shared__ float s_infl[172];
  __shared__ float s_wc[128];
  __shared__ float s_pw[768];
  __shared__ __attribute__((aligned(16))) unsigned short s_bufA[12288]; // Wqkv[192][64] -> P[96][104]
  __shared__ __attribute__((aligned(16))) unsigned short s_bufB[6144];  // T[96][64]    -> ctx[96][64]
  __shared__ __attribute__((aligned(16))) unsigned short s_q[6144];     // q[96][64]    -> AO[96][64]
  __shared__ __attribute__((aligned(16))) unsigned short s_km[6144];    // k[96][64]    -> Wa[64][64]
  __shared__ __attribute__((aligned(16))) unsigned short s_v[6656];     // v[64][104]

  const int b = blockIdx.x, tid = threadIdx.x;
  const int w = tid >> 6, lane = tid & 63;
  const int g = lane >> 4, lm = lane & 15;
  const f32x4 zf4 = {0.f, 0.f, 0.f, 0.f};
  const bf16x8 z8 = {0, 0, 0, 0, 0, 0, 0, 0};

  // ---- stage small + Wqkv (swizzled) ----
  for (int i = tid; i < 172; i += 256) s_infl[i] = influence[b * 172 + i] * 0.1f;
  for (int i = tid; i < 128; i += 256) s_wc[i] = Wc[i];
  for (int i = tid; i < 768; i += 256) s_pw[i] = pw[i];
  {
    const uint4* wq4 = (const uint4*)wqkv_t;
    for (int i = tid; i < 1536; i += 256) {
      uint4 x = wq4[i];
      int e = i * 8, n = e >> 6, d = e & 63;
      *(uint4*)&s_bufA[n * 64 + (d ^ ((n & 7) << 3))] = x;
    }
  }
  __syncthreads();

  // ---- tokens (bf16, swizzled) ----
  for (int i = tid; i < SPAD * 64; i += 256) {
    int s = i >> 6, d = i & 63;
    float v = 0.f;
    if (s < S86)
      v = fmaxf(s_infl[s] * s_wc[d] + s_infl[86 + s] * s_wc[64 + d] + sp[i], 0.f);
    s_bufB[(s << 6) | (d ^ ((s & 7) << 3))] = f2bf(v);
  }
  __syncthreads();

  // ---- qkv GEMM: wave w owns nt = 3w..3w+2 ----
  {
    f32x4 acc[6][3];
    #pragma unroll
    for (int mt = 0; mt < 6; ++mt)
      #pragma unroll
      for (int j = 0; j < 3; ++j) acc[mt][j] = zf4;

    #pragma unroll
    for (int ks = 0; ks < 2; ++ks)
      #pragma unroll
      for (int mt = 0; mt < 6; ++mt) {
        int m = mt * 16 + lm;
        bf16x8 a = *(const bf16x8*)&s_bufB[m * 64 + ((ks * 32 + g * 8) ^ ((m & 7) << 3))];
        #pragma unroll
        for (int j = 0; j < 3; ++j) {
          int n = (3 * w + j) * 16 + lm;
          bf16x8 bb = *(const bf16x8*)&s_bufA[n * 64 + ((ks * 32 + g * 8) ^ ((n & 7) << 3))];
          acc[mt][j] = MFMA(a, bb, acc[mt][j]);
        }
      }

    #pragma unroll
    for (int j = 0; j < 3; ++j) {
      int n = (3 * w + j) * 16 + lm;
      float bias = bqkv[n];
      #pragma unroll
      for (int mt = 0; mt < 6; ++mt)
        #pragma unroll
        for (int r = 0; r < 4; ++r) {
          int m = mt * 16 + 4 * g + r;
          unsigned short hv = f2bf(acc[mt][j][r] + bias);
          if (n < 64)        s_q[m * 64 + (n ^ ((m & 7) << 3))] = hv;
          else if (n < 128) { int d = n - 64;  s_km[m * 64 + (d ^ ((m & 7) << 3))] = hv; }
          else              { int d = n - 128; s_v[d * 104 + m] = hv; }
        }
    }
  }
  __syncthreads();

  // ---- attention, heads sequential; wave w owns mt in {w, w+4} ----
  for (int h = 0; h < 4; ++h) {
    #pragma unroll
    for (int mi = 0; mi < 2; ++mi) {
      int mt = w + mi * 4;
      if (mt <= 5) {
        int m = mt * 16 + lm;
        bf16x8 a = *(const bf16x8*)&s_q[m * 64 + ((h * 16 + (g & 1) * 8) ^ ((m & 7) << 3))];
        if (g >= 2) a = z8;  // K=16 padded to 32 with zeros in-register
        f32x4 sc[6];
        #pragma unroll
        for (int nt = 0; nt < 6; ++nt) {
          int n = nt * 16 + lm;
          bf16x8 bb = *(const bf16x8*)&s_km[n * 64 + ((h * 16 + (g & 1) * 8) ^ ((n & 7) << 3))];
          sc[nt] = MFMA(a, bb, zf4);
        }
        // register softmax: lane holds rows mt*16+4g+r, cols nt*16+lm
        #pragma unroll
        for (int r = 0; r < 4; ++r) {
          float mx = -1e30f;
          #pragma unroll
          for (int nt = 0; nt < 6; ++nt) {
            float v = sc[nt][r] * 0.25f;   // 1/sqrt(16)
            sc[nt][r] = v;
            if (nt * 16 + lm < S86) mx = fmaxf(mx, v);
          }
          mx = fmaxf(mx, __shfl_xor(mx, 1));
          mx = fmaxf(mx, __shfl_xor(mx, 2));
          mx = fmaxf(mx, __shfl_xor(mx, 4));
          mx = fmaxf(mx, __shfl_xor(mx, 8));
          float sum = 0.f;
          #pragma unroll
          for (int nt = 0; nt < 6; ++nt) {
            float e = (nt * 16 + lm < S86) ? __expf(sc[nt][r] - mx) : 0.f;
            sc[nt][r] = e;
            sum += e;
          }
          sum += __shfl_xor(sum, 1);
          sum += __shfl_xor(sum, 2);
          sum += __shfl_xor(sum, 4);
          sum += __shfl_xor(sum, 8);
          float inv = 1.0f / sum;
          int mrow = mt * 16 + 4 * g + r;
          #pragma unroll
          for (int nt = 0; nt < 6; ++nt)
            s_bufA[mrow * 104 + nt * 16 + lm] = f2bf(sc[nt][r] * inv);
        }
      }
    }
    __syncthreads();
    // ctx = P @ V^T(stored [hd][kv])
    #pragma unroll
    for (int mi = 0; mi < 2; ++mi) {
      int mt = w + mi * 4;
      if (mt <= 5) {
        int m = mt * 16 + lm;
        f32x4 ca = zf4;
        #pragma unroll
        for (int ks = 0; ks < 3; ++ks) {
          bf16x8 a  = *(const bf16x8*)&s_bufA[m * 104 + ks * 32 + g * 8];
          bf16x8 bb = *(const bf16x8*)&s_v[(h * 16 + lm) * 104 + ks * 32 + g * 8];
          ca = MFMA(a, bb, ca);
        }
        #pragma unroll
        for (int r = 0; r < 4; ++r) {
          int mrow = mt * 16 + 4 * g + r;
          int d = h * 16 + lm;
          s_bufB[mrow * 64 + (d ^ ((mrow & 7) << 3))] = f2bf(ca[r]);
        }
      }
    }
    __syncthreads();
  }

  // ---- stage Wa (into s_km) ----
  {
    const uint4* wa4 = (const uint4*)wa_t;
    for (int i = tid; i < 512; i += 256) {
      uint4 x = wa4[i];
      int e = i * 8, n = e >> 6, d = e & 63;
      *(uint4*)&s_km[n * 64 + (d ^ ((n & 7) << 3))] = x;
    }
  }
  __syncthreads();

  // ---- attn_out GEMM: wave w owns nt = w ----
  {
    f32x4 oacc[6];
    #pragma unroll
    for (int mt = 0; mt < 6; ++mt) oacc[mt] = zf4;
    int n = w * 16 + lm;
    #pragma unroll
    for (int ks = 0; ks < 2; ++ks) {
      bf16x8 bb = *(const bf16x8*)&s_km[n * 64 + ((ks * 32 + g * 8) ^ ((n & 7) << 3))];
      #pragma unroll
      for (int mt = 0; mt < 6; ++mt) {
        int m = mt * 16 + lm;
        bf16x8 a = *(const bf16x8*)&s_bufB[m * 64 + ((ks * 32 + g * 8) ^ ((m & 7) << 3))];
        oacc[mt] = MFMA(a, bb, oacc[mt]);
      }
    }
    float bias = ba[n];
    #pragma unroll
    for (int mt = 0; mt < 6; ++mt)
      #pragma unroll
      for (int r = 0; r < 4; ++r) {
        int m = mt * 16 + 4 * g + r;
        s_q[m * 64 + (n ^ ((m & 7) << 3))] = f2bf(oacc[mt][r] + bias);
      }
  }
  __syncthreads();

  // ---- pooling (global mean + 7 region means) -> concat bf16 to ws ----
  #pragma unroll
  for (int pass = 0; pass < 2; ++pass) {
    int idx = pass * 256 + tid;           // 0..511
    int p = idx >> 6, d = idx & 63;
    float acc = 0.f;
    for (int s = 0; s < S86; ++s)
      acc += s_pw[p * 96 + s] * bf2f(s_q[s * 64 + (d ^ ((s & 7) << 3))]);
    c_ws[b * 512 + idx] = f2bf(acc);
  }
}

// ============================================================ final GEMM: (8192x512)@(512x128)
__global__ __launch_bounds__(256, 2) void final_gemm(
    const unsigned short* __restrict__ c_ws, const unsigned short* __restrict__ wo_t,
    const float* __restrict__ bo, float* __restrict__ out) {
  __shared__ __attribute__((aligned(16))) unsigned short sA[32 * 512];
  __shared__ __attribute__((aligned(16))) unsigned short sB[128 * 40];
  const int tid = threadIdx.x, w = tid >> 6, lane = tid & 63;
  const int g = lane >> 4, lm = lane & 15;
  const int rb = blockIdx.x * 32;
  const f32x4 zf4 = {0.f, 0.f, 0.f, 0.f};

  const uint4* c4 = (const uint4*)c_ws;
  #pragma unroll
  for (int ii = 0; ii < 8; ++ii) {
    int i = ii * 256 + tid;
    int e = i * 8, m = e >> 9, d = e & 511;
    uint4 x = c4[(rb + m) * 64 + (d >> 3)];
    *(uint4*)&sA[m * 512 + (d ^ ((m & 7) << 3))] = x;
  }

  const int mt = w >> 1;
  const int ntb = (w & 1) * 4;
  f32x4 acc[4];
  #pragma unroll
  for (int j = 0; j < 4; ++j) acc[j] = zf4;

  const uint4* wo4 = (const uint4*)wo_t;
  for (int ks = 0; ks < 16; ++ks) {
    __syncthreads();                       // sA ready (ks=0) / sB consumers done
    #pragma unroll
    for (int ii = 0; ii < 2; ++ii) {
      int i = ii * 256 + tid;
      int n = i >> 2, kk = (i & 3) * 8;
      uint4 x = wo4[n * 64 + ks * 4 + (kk >> 3)];
      *(uint4*)&sB[n * 40 + kk] = x;
    }
    __syncthreads();
    int m = mt * 16 + lm;
    bf16x8 a = *(const bf16x8*)&sA[m * 512 + ((ks * 32 + g * 8) ^ ((m & 7) << 3))];
    #pragma unroll
    for (int j = 0; j < 4; ++j) {
      int n = (ntb + j) * 16 + lm;
      bf16x8 bb = *(const bf16x8*)&sB[n * 40 + g * 8];
      acc[j] = MFMA(a, bb, acc[j]);
    }
  }

  #pragma unroll
  for (int j = 0; j < 4; ++j) {
    int n = (ntb + j) * 16 + lm;
    float bias = bo[n];
    #pragma unroll
    for (int r = 0; r < 4; ++r) {
      int m = rb + mt * 16 + 4 * g + r;
      out[m * 128 + n] = fmaxf(acc[j][r] + bias, 0.f);
    }
  }
}

// ============================================================ launch
extern "C" void kernel_launch(void* const* d_in, const int* in_sizes, int n_in,
                              void* d_out, int out_size, void* d_ws, size_t ws_size,
                              hipStream_t stream) {
  const float* influence = (const float*)d_in[0];
  const float* cstat     = (const float*)d_in[1];
  const float* Wc        = (const float*)d_in[2];
  const float* bc        = (const float*)d_in[3];
  const float* Wqkv      = (const float*)d_in[4];
  const float* bqkv      = (const float*)d_in[5];
  const float* Wa        = (const float*)d_in[6];
  const float* ba        = (const float*)d_in[7];
  const float* Wo        = (const float*)d_in[8];
  const float* bo        = (const float*)d_in[9];
  float* out = (float*)d_out;
  char* ws = (char*)d_ws;

  float* sp              = (float*)(ws + OFF_SP);
  float* pw              = (float*)(ws + OFF_PW);
  unsigned short* wqkv_t = (unsigned short*)(ws + OFF_WQKV);
  unsigned short* wa_t   = (unsigned short*)(ws + OFF_WA);
  unsigned short* wo_t   = (unsigned short*)(ws + OFF_WO);
  unsigned short* c_ws   = (unsigned short*)(ws + OFF_C);

  hipLaunchKernelGGL(prologue, dim3(36), dim3(256), 0, stream,
                     cstat, Wc, bc, Wqkv, Wa, Wo, sp, pw, wqkv_t, wa_t, wo_t);
  hipLaunchKernelGGL(fused, dim3(B_TOT), dim3(256), 0, stream,
                     influence, Wc, bqkv, ba, sp, pw, wqkv_t, wa_t, c_ws);
  hipLaunchKernelGGL(final_gemm, dim3(256), dim3(256), 0, stream,
                     c_ws, wo_t, bo, out);
}

// Round 2
// 437.540 us; speedup vs baseline: 1.3765x; 1.3765x over previous
//
#include <hip/hip_runtime.h>

// ---------- shapes ----------
#define B_TOT 8192
#define S86   86

using bf16x8 = __attribute__((ext_vector_type(8))) short;
using u16x8  = __attribute__((ext_vector_type(8))) unsigned short;
using f32x4  = __attribute__((ext_vector_type(4))) float;

#define MFMA(a, b, c) __builtin_amdgcn_mfma_f32_16x16x32_bf16((a), (b), (c), 0, 0, 0)

__device__ inline unsigned short f2bf(float f) {
  unsigned int u = __float_as_uint(f);
  u += 0x7fff + ((u >> 16) & 1);          // RNE
  return (unsigned short)(u >> 16);
}

// ---------- ws layout (bytes) ----------
#define OFF_SP    0          // 86*64 f32   -> 22016
#define OFF_PWM   22016      // 16*96 bf16  -> 3072
#define OFF_INVC  25088      // 8 f32       -> 32
#define OFF_WQKV  25120      // 192*64 bf16 -> 24576
#define OFF_WA    49696      // 64*64 bf16  -> 8192
#define OFF_WO    57888      // 128*512 bf16-> 131072
#define OFF_C     188960     // 8192*512 bf16 -> 8388608

// ============================================================ prologue
__global__ void prologue(const float* __restrict__ cstat, const float* __restrict__ Wc,
                         const float* __restrict__ bc, const float* __restrict__ Wqkv,
                         const float* __restrict__ Wa, const float* __restrict__ Wo,
                         float* __restrict__ sp, unsigned short* __restrict__ pwm,
                         float* __restrict__ invc,
                         unsigned short* __restrict__ wqkv_t,
                         unsigned short* __restrict__ wa_t,
                         unsigned short* __restrict__ wo_t) {
  const int b = blockIdx.x, tid = threadIdx.x;
  if (b < 32) {                       // Wo (512,128) -> wo_t [128][512] bf16
    #pragma unroll
    for (int ii = 0; ii < 8; ++ii) {
      int idx = ii * 256 + tid;
      int kl = idx >> 7, n = idx & 127;
      int k = b * 16 + kl;
      wo_t[n * 512 + k] = f2bf(Wo[k * 128 + n]);
    }
  } else if (b == 32) {               // static part of token projection (f32)
    for (int i = tid; i < S86 * 64; i += 256) {
      int s = i >> 6, d = i & 63;
      float v = bc[d];
      #pragma unroll
      for (int f = 0; f < 11; ++f) v += cstat[s * 11 + f] * Wc[(2 + f) * 64 + d];
      sp[i] = v;
    }
  } else if (b == 33) {               // Wqkv (64,192) -> wqkv_t [192][64]
    for (int i = tid; i < 64 * 192; i += 256) {
      int k = i / 192, n = i % 192;
      wqkv_t[n * 64 + k] = f2bf(Wqkv[i]);
    }
  } else if (b == 34) {               // Wa (64,64) -> wa_t [64][64]
    for (int i = tid; i < 64 * 64; i += 256) {
      int k = i >> 6, n = i & 63;
      wa_t[n * 64 + k] = f2bf(Wa[i]);
    }
  } else {                            // binary pool masks [16][96] bf16 + invc[8]
    __shared__ float rcnt[7];
    if (tid < 7) {
      int c = 0;
      for (int s = 0; s < S86; ++s) c += (cstat[s * 11 + 2 + tid] > 0.5f) ? 1 : 0;
      rcnt[tid] = 1.0f / (float)(c < 1 ? 1 : c);
    }
    __syncthreads();
    for (int i = tid; i < 16 * 96; i += 256) {
      int p = i / 96, s = i - p * 96;
      float v = 0.f;
      if (p < 8 && s < S86)
        v = (p == 0) ? 1.f : ((cstat[s * 11 + 1 + p] > 0.5f) ? 1.f : 0.f);
      pwm[i] = f2bf(v);   // 0/1 exact in bf16
    }
    if (tid < 8) invc[tid] = (tid == 0) ? (1.0f / 86.0f) : rcnt[tid - 1];
  }
}

// ============================================================ fused per-batch kernel
// 384 threads = 6 waves; wave w owns output rows 16w..16w+15 through the whole
// attention->AO pipeline => P/ctx/AO are wave-local => only 3 barriers total.
__global__ __launch_bounds__(384, 3) void fused(
    const float* __restrict__ influence, const float* __restrict__ Wc,
    const float* __restrict__ sp, const float* __restrict__ bqkv,
    const float* __restrict__ ba, const float* __restrict__ invc,
    const unsigned short* __restrict__ wqkv_t,
    const unsigned short* __restrict__ wa_t,
    const unsigned short* __restrict__ pwm,
    unsigned short* __restrict__ c_ws) {

  __shared__ __attribute__((aligned(16))) unsigned short s_tok[96 * 64];  // tokens -> ctx
  __shared__ __attribute__((aligned(16))) unsigned short s_q[96 * 64];
  __shared__ __attribute__((aligned(16))) unsigned short s_k[96 * 64];
  __shared__ __attribute__((aligned(16))) unsigned short s_v[64 * 96];    // [hd][kv]
  __shared__ __attribute__((aligned(16))) unsigned short s_p[6 * 16 * 104]; // per-wave P
  __shared__ __attribute__((aligned(16))) unsigned short s_aoT[64 * 96];  // [d][m]

  const int b = blockIdx.x, tid = threadIdx.x;
  const int w = tid >> 6, lane = tid & 63;
  const int g = lane >> 4, lm = lane & 15;
  const f32x4 zf4 = {0.f, 0.f, 0.f, 0.f};
  const bf16x8 z8 = {0, 0, 0, 0, 0, 0, 0, 0};

  // ---- tokens (relu(dyn@Wc[0:2] + sp)), bf16, XOR-swizzled [96][64] ----
  #pragma unroll
  for (int it = 0; it < 2; ++it) {
    int i = it * 384 + tid;            // 0..767 vec8 elems
    int s = i >> 3, d0 = (i & 7) << 3;
    u16x8 o;
    if (s < S86) {
      float iu = influence[b * 172 + s] * 0.1f;
      float iv = influence[b * 172 + 86 + s] * 0.1f;
      #pragma unroll
      for (int jj = 0; jj < 8; ++jj) {
        int d = d0 + jj;
        float v = fmaxf(iu * Wc[d] + iv * Wc[64 + d] + sp[s * 64 + d], 0.f);
        o[jj] = f2bf(v);
      }
    } else {
      o = (u16x8){0, 0, 0, 0, 0, 0, 0, 0};
    }
    *(u16x8*)&s_tok[s * 64 + (d0 ^ ((s & 7) << 3))] = o;
  }
  __syncthreads();                     // BAR 1

  // ---- qkv GEMM: wave w owns n = 32w..32w+31 (B-frags direct from global) ----
  {
    bf16x8 bf0[2], bf1[2];
    #pragma unroll
    for (int ks = 0; ks < 2; ++ks) {
      int n0 = (2 * w) * 16 + lm, n1 = (2 * w + 1) * 16 + lm;
      bf0[ks] = *(const bf16x8*)&wqkv_t[n0 * 64 + ks * 32 + g * 8];
      bf1[ks] = *(const bf16x8*)&wqkv_t[n1 * 64 + ks * 32 + g * 8];
    }
    f32x4 acc0[6], acc1[6];
    #pragma unroll
    for (int mt = 0; mt < 6; ++mt) { acc0[mt] = zf4; acc1[mt] = zf4; }
    #pragma unroll
    for (int ks = 0; ks < 2; ++ks)
      #pragma unroll
      for (int mt = 0; mt < 6; ++mt) {
        int m = mt * 16 + lm;
        bf16x8 a = *(const bf16x8*)&s_tok[m * 64 + ((ks * 32 + g * 8) ^ ((m & 7) << 3))];
        acc0[mt] = MFMA(a, bf0[ks], acc0[mt]);
        acc1[mt] = MFMA(a, bf1[ks], acc1[mt]);
      }
    #pragma unroll
    for (int j = 0; j < 2; ++j) {
      int n = (2 * w + j) * 16 + lm;
      float bias = bqkv[n];
      #pragma unroll
      for (int mt = 0; mt < 6; ++mt) {
        f32x4 av = j ? acc1[mt] : acc0[mt];
        #pragma unroll
        for (int r = 0; r < 4; ++r) {
          int m = mt * 16 + 4 * g + r;
          float v = av[r] + bias;
          if (w < 2) {                 // q, pre-scaled by 1/sqrt(hd)
            s_q[m * 64 + (n ^ ((m & 7) << 3))] = f2bf(v * 0.25f);
          } else if (w < 4) {
            int d = n - 64;
            s_k[m * 64 + (d ^ ((m & 7) << 3))] = f2bf(v);
          } else {
            int d = n - 128;
            s_v[d * 96 + m] = f2bf(v);
          }
        }
      }
    }
  }
  __syncthreads();                     // BAR 2

  // ---- attention: wave-local rows, zero barriers ----
  unsigned short* pb = &s_p[w * 16 * 104];
  #pragma unroll
  for (int h = 0; h < 4; ++h) {
    int m = 16 * w + lm;
    int koff = h * 16 + (g & 1) * 8;   // K=16 padded to 32, zero A for g>=2
    bf16x8 a = *(const bf16x8*)&s_q[m * 64 + (koff ^ ((m & 7) << 3))];
    if (g >= 2) a = z8;
    f32x4 sc[6];
    #pragma unroll
    for (int nt = 0; nt < 6; ++nt) {
      int n = nt * 16 + lm;
      bf16x8 bb = *(const bf16x8*)&s_k[n * 64 + (koff ^ ((n & 7) << 3))];
      sc[nt] = MFMA(a, bb, zf4);
    }
    // register softmax (no max-sub: |scores| << 1), P unnormalized
    float inv[4];
    #pragma unroll
    for (int r = 0; r < 4; ++r) {
      float e[6], sum = 0.f;
      #pragma unroll
      for (int nt = 0; nt < 6; ++nt) {
        float x = __expf(sc[nt][r]);
        if (nt == 5 && lm >= 6) x = 0.f;   // mask cols 86..95
        e[nt] = x; sum += x;
      }
      sum += __shfl_xor(sum, 1);
      sum += __shfl_xor(sum, 2);
      sum += __shfl_xor(sum, 4);
      sum += __shfl_xor(sum, 8);
      inv[r] = __builtin_amdgcn_rcpf(sum);
      int lr = 4 * g + r;
      #pragma unroll
      for (int nt = 0; nt < 6; ++nt)
        pb[lr * 104 + nt * 16 + lm] = f2bf(e[nt]);
    }
    // PV (wave-local P rows; v shared read-only)
    f32x4 ca = zf4;
    #pragma unroll
    for (int ks = 0; ks < 3; ++ks) {
      bf16x8 pa = *(const bf16x8*)&pb[lm * 104 + ks * 32 + g * 8];
      bf16x8 vb = *(const bf16x8*)&s_v[(h * 16 + lm) * 96 + ks * 32 + g * 8];
      ca = MFMA(pa, vb, ca);
    }
    #pragma unroll
    for (int r = 0; r < 4; ++r) {      // normalize + write ctx (wave-local rows)
      int mm = 16 * w + 4 * g + r;
      int d = h * 16 + lm;
      s_tok[mm * 64 + (d ^ ((mm & 7) << 3))] = f2bf(ca[r] * inv[r]);
    }
  }

  // ---- attn_out GEMM (wave-local rows, Wa direct from global) -> AO^T ----
  {
    int m = 16 * w + lm;
    bf16x8 a0 = *(const bf16x8*)&s_tok[m * 64 + ((g * 8) ^ ((m & 7) << 3))];
    bf16x8 a1 = *(const bf16x8*)&s_tok[m * 64 + ((32 + g * 8) ^ ((m & 7) << 3))];
    f32x4 acc[4];
    #pragma unroll
    for (int nt = 0; nt < 4; ++nt) acc[nt] = zf4;
    #pragma unroll
    for (int nt = 0; nt < 4; ++nt) {
      int n = nt * 16 + lm;
      bf16x8 b0 = *(const bf16x8*)&wa_t[n * 64 + g * 8];
      bf16x8 b1 = *(const bf16x8*)&wa_t[n * 64 + 32 + g * 8];
      acc[nt] = MFMA(a0, b0, acc[nt]);
      acc[nt] = MFMA(a1, b1, acc[nt]);
    }
    #pragma unroll
    for (int nt = 0; nt < 4; ++nt) {
      int n = nt * 16 + lm;
      float bias = ba[n];
      #pragma unroll
      for (int r = 0; r < 4; ++r) {
        int mm = 16 * w + 4 * g + r;
        s_aoT[n * 96 + mm] = f2bf(acc[nt][r] + bias);
      }
    }
  }
  __syncthreads();                     // BAR 3

  // ---- pooling via MFMA: [16 pools pad][96 s] @ AO^T[64][96] ----
  if (w < 4) {
    f32x4 pc = zf4;
    #pragma unroll
    for (int ks = 0; ks < 3; ++ks) {
      bf16x8 pa = *(const bf16x8*)&pwm[lm * 96 + ks * 32 + g * 8];
      bf16x8 ab = *(const bf16x8*)&s_aoT[(w * 16 + lm) * 96 + ks * 32 + g * 8];
      pc = MFMA(pa, ab, pc);
    }
    if (g < 2) {
      #pragma unroll
      for (int r = 0; r < 4; ++r) {
        int p = 4 * g + r;             // 0..7
        c_ws[b * 512 + p * 64 + w * 16 + lm] = f2bf(pc[r] * invc[p]);
      }
    }
  }
}

// ============================================================ final GEMM: (8192x512)@(512x128)
// 512 blocks x 16 rows; Wo fragments streamed from L2, no inner barriers.
__global__ __launch_bounds__(256, 4) void final_gemm(
    const unsigned short* __restrict__ c_ws, const unsigned short* __restrict__ wo_t,
    const float* __restrict__ bo, float* __restrict__ out) {
  __shared__ __attribute__((aligned(16))) unsigned short sA[16 * 512];
  const int tid = threadIdx.x, w = tid >> 6, lane = tid & 63;
  const int g = lane >> 4, lm = lane & 15;
  const int rb = blockIdx.x * 16;
  const f32x4 zf4 = {0.f, 0.f, 0.f, 0.f};

  const uint4* c4 = (const uint4*)c_ws;
  #pragma unroll
  for (int ii = 0; ii < 4; ++ii) {
    int i = ii * 256 + tid;            // 0..1023
    int m = i >> 6, d0 = (i & 63) << 3;
    uint4 x = c4[(long)(rb + m) * 64 + (d0 >> 3)];
    *(uint4*)&sA[m * 512 + (d0 ^ ((m & 7) << 3))] = x;
  }
  __syncthreads();

  f32x4 acc0 = zf4, acc1 = zf4;
  const int n0 = (2 * w) * 16 + lm, n1 = (2 * w + 1) * 16 + lm;
  #pragma unroll 4
  for (int ks = 0; ks < 16; ++ks) {
    bf16x8 a = *(const bf16x8*)&sA[lm * 512 + ((ks * 32 + g * 8) ^ ((lm & 7) << 3))];
    bf16x8 b0 = *(const bf16x8*)&wo_t[n0 * 512 + ks * 32 + g * 8];
    bf16x8 b1 = *(const bf16x8*)&wo_t[n1 * 512 + ks * 32 + g * 8];
    acc0 = MFMA(a, b0, acc0);
    acc1 = MFMA(a, b1, acc1);
  }
  float bias0 = bo[n0], bias1 = bo[n1];
  #pragma unroll
  for (int r = 0; r < 4; ++r) {
    int mm = rb + 4 * g + r;
    out[mm * 128 + n0] = fmaxf(acc0[r] + bias0, 0.f);
    out[mm * 128 + n1] = fmaxf(acc1[r] + bias1, 0.f);
  }
}

// ============================================================ launch
extern "C" void kernel_launch(void* const* d_in, const int* in_sizes, int n_in,
                              void* d_out, int out_size, void* d_ws, size_t ws_size,
                              hipStream_t stream) {
  const float* influence = (const float*)d_in[0];
  const float* cstat     = (const float*)d_in[1];
  const float* Wc        = (const float*)d_in[2];
  const float* bc        = (const float*)d_in[3];
  const float* Wqkv      = (const float*)d_in[4];
  const float* bqkv      = (const float*)d_in[5];
  const float* Wa        = (const float*)d_in[6];
  const float* ba        = (const float*)d_in[7];
  const float* Wo        = (const float*)d_in[8];
  const float* bo        = (const float*)d_in[9];
  float* out = (float*)d_out;
  char* ws = (char*)d_ws;

  float* sp              = (float*)(ws + OFF_SP);
  unsigned short* pwm    = (unsigned short*)(ws + OFF_PWM);
  float* invc            = (float*)(ws + OFF_INVC);
  unsigned short* wqkv_t = (unsigned short*)(ws + OFF_WQKV);
  unsigned short* wa_t   = (unsigned short*)(ws + OFF_WA);
  unsigned short* wo_t   = (unsigned short*)(ws + OFF_WO);
  unsigned short* c_ws   = (unsigned short*)(ws + OFF_C);

  hipLaunchKernelGGL(prologue, dim3(36), dim3(256), 0, stream,
                     cstat, Wc, bc, Wqkv, Wa, Wo, sp, pwm, invc, wqkv_t, wa_t, wo_t);
  hipLaunchKernelGGL(fused, dim3(B_TOT), dim3(384), 0, stream,
                     influence, Wc, sp, bqkv, ba, invc, wqkv_t, wa_t, pwm, c_ws);
  hipLaunchKernelGGL(final_gemm, dim3(512), dim3(256), 0, stream,
                     c_ws, wo_t, bo, out);
}

// Round 8
// 405.328 us; speedup vs baseline: 1.4859x; 1.0795x over previous
//
#include <hip/hip_runtime.h>

// ---------- shapes ----------
#define B_TOT 8192
#define S86   86

using bf16x8 = __attribute__((ext_vector_type(8))) short;
using u16x8  = __attribute__((ext_vector_type(8))) unsigned short;
using f32x4  = __attribute__((ext_vector_type(4))) float;

#define MFMA(a, b, c) __builtin_amdgcn_mfma_f32_16x16x32_bf16((a), (b), (c), 0, 0, 0)

__device__ inline unsigned short f2bf(float f) {
  unsigned int u = __float_as_uint(f);
  u += 0x7fff + ((u >> 16) & 1);          // RNE
  return (unsigned short)(u >> 16);
}
__device__ inline unsigned int cvtpk(float lo, float hi) {
  unsigned int r;
  asm("v_cvt_pk_bf16_f32 %0, %1, %2" : "=v"(r) : "v"(lo), "v"(hi));
  return r;
}
// g-group exchange: route packed bf16 pairs (lo=even tile, hi=odd tile) so each
// lane assembles its B-fragment slots i=0..7 (k = 32ks+8g+i). Derived from the
// verified C/D layout row=16mt+4g+r,col=lm.
__device__ inline bf16x8 xchg(unsigned p0, unsigned p1, unsigned p2, unsigned p3,
                              int slo, int shi, unsigned psel) {
  unsigned l0 = (unsigned)__shfl((int)p0, slo);
  unsigned l1 = (unsigned)__shfl((int)p1, slo);
  unsigned l2 = (unsigned)__shfl((int)p2, slo);
  unsigned l3 = (unsigned)__shfl((int)p3, slo);
  unsigned h0 = (unsigned)__shfl((int)p0, shi);
  unsigned h1 = (unsigned)__shfl((int)p1, shi);
  unsigned h2 = (unsigned)__shfl((int)p2, shi);
  unsigned h3 = (unsigned)__shfl((int)p3, shi);
  uint4 u;
  u.x = __builtin_amdgcn_perm(l1, l0, psel);
  u.y = __builtin_amdgcn_perm(l3, l2, psel);
  u.z = __builtin_amdgcn_perm(h1, h0, psel);
  u.w = __builtin_amdgcn_perm(h3, h2, psel);
  return __builtin_bit_cast(bf16x8, u);
}

// ---------- ws layout (bytes) ----------
#define OFF_SP    0          // 86*64 f32   -> 22016
#define OFF_PWM   22016      // 16*96 bf16  -> 3072
#define OFF_INVC  25088      // 8 f32       -> 32
#define OFF_WQKV  25120      // 192*64 bf16 -> 24576
#define OFF_WA    49696      // 64*64 bf16  -> 8192
#define OFF_WO    57888      // 128*512 bf16-> 131072

// ============================================================ prologue
__global__ void prologue(const float* __restrict__ cstat, const float* __restrict__ Wc,
                         const float* __restrict__ bc, const float* __restrict__ Wqkv,
                         const float* __restrict__ Wa, const float* __restrict__ Wo,
                         float* __restrict__ sp, unsigned short* __restrict__ pwm,
                         float* __restrict__ invc,
                         unsigned short* __restrict__ wqkv_t,
                         unsigned short* __restrict__ wa_t,
                         unsigned short* __restrict__ wo_t) {
  const int b = blockIdx.x, tid = threadIdx.x;
  if (b < 32) {                       // Wo (512,128) -> wo_t [128][512] bf16
    #pragma unroll
    for (int ii = 0; ii < 8; ++ii) {
      int idx = ii * 256 + tid;
      int kl = idx >> 7, n = idx & 127;
      int k = b * 16 + kl;
      wo_t[n * 512 + k] = f2bf(Wo[k * 128 + n]);
    }
  } else if (b == 32) {               // static part of token projection (f32)
    for (int i = tid; i < S86 * 64; i += 256) {
      int s = i >> 6, d = i & 63;
      float v = bc[d];
      #pragma unroll
      for (int f = 0; f < 11; ++f) v += cstat[s * 11 + f] * Wc[(2 + f) * 64 + d];
      sp[i] = v;
    }
  } else if (b == 33) {               // Wqkv (64,192) -> wqkv_t [192][64]
    for (int i = tid; i < 64 * 192; i += 256) {
      int k = i / 192, n = i % 192;
      wqkv_t[n * 64 + k] = f2bf(Wqkv[i]);
    }
  } else if (b == 34) {               // Wa (64,64) -> wa_t [64][64] = Wa^T
    for (int i = tid; i < 64 * 64; i += 256) {
      int k = i >> 6, n = i & 63;
      wa_t[n * 64 + k] = f2bf(Wa[i]);
    }
  } else {                            // binary pool masks [16][96] bf16 + invc[8]
    __shared__ float rcnt[7];
    if (tid < 7) {
      int c = 0;
      for (int s = 0; s < S86; ++s) c += (cstat[s * 11 + 2 + tid] > 0.5f) ? 1 : 0;
      rcnt[tid] = 1.0f / (float)(c < 1 ? 1 : c);
    }
    __syncthreads();
    for (int i = tid; i < 16 * 96; i += 256) {
      int p = i / 96, s = i - p * 96;
      float v = 0.f;
      if (p < 8 && s < S86)
        v = (p == 0) ? 1.f : ((cstat[s * 11 + 1 + p] > 0.5f) ? 1.f : 0.f);
      pwm[i] = f2bf(v);   // 0/1 exact in bf16
    }
    if (tid < 8) invc[tid] = (tid == 0) ? (1.0f / 86.0f) : rcnt[tid - 1];
  }
}

// ============================================================ fused per-batch kernel
// 6 waves. Transposed attention: S^T = MFMA(K, Q) => lane owns one q-column
// => lane-local softmax, in-register P/ctx via g-group exchange. LDS 51200 B.
// Final 512x128 GEMV folded in (broadcast-B MFMA vs Wo in L2).
__global__ __launch_bounds__(384, 3) void fused(
    const float* __restrict__ influence, const float* __restrict__ Wc,
    const float* __restrict__ sp, const float* __restrict__ bqkv,
    const float* __restrict__ ba, const float* __restrict__ invc,
    const float* __restrict__ bo,
    const unsigned short* __restrict__ wqkv_t,
    const unsigned short* __restrict__ wa_t,
    const unsigned short* __restrict__ pwm,
    const unsigned short* __restrict__ wo_t,
    float* __restrict__ out) {

  __shared__ __attribute__((aligned(16))) unsigned short s_r1[6656]; // T[96][64] -> aoT[64][104]
  __shared__ __attribute__((aligned(16))) unsigned short s_q[6144];  // q[96][64]
  __shared__ __attribute__((aligned(16))) unsigned short s_r2[6144]; // k[96][64] -> concat[512]
  __shared__ __attribute__((aligned(16))) unsigned short s_v[6656];  // v^T[64][104]

  unsigned short* sT  = s_r1;   // stride 64, swizzled
  unsigned short* sAO = s_r1;   // stride 104
  unsigned short* sK  = s_r2;   // stride 64, swizzled
  unsigned short* sCC = s_r2;   // concat 512

  const int b = blockIdx.x, tid = threadIdx.x;
  const int w = tid >> 6, lane = tid & 63;
  const int g = lane >> 4, lm = lane & 15;
  const f32x4 zf4 = {0.f, 0.f, 0.f, 0.f};
  const bf16x8 z8 = {0, 0, 0, 0, 0, 0, 0, 0};

  // ---- tokens: relu(dyn@Wc[0:2] + sp), bf16, XOR-swizzled [96][64] ----
  #pragma unroll
  for (int it = 0; it < 2; ++it) {
    int i = it * 384 + tid;            // 0..767 vec8 elems
    int s = i >> 3, d0 = (i & 7) << 3;
    u16x8 o;
    if (s < S86) {
      float iu = influence[b * 172 + s] * 0.1f;
      float iv = influence[b * 172 + 86 + s] * 0.1f;
      #pragma unroll
      for (int jj = 0; jj < 8; ++jj) {
        int d = d0 + jj;
        float v = fmaxf(iu * Wc[d] + iv * Wc[64 + d] + sp[s * 64 + d], 0.f);
        o[jj] = f2bf(v);
      }
    } else {
      o = (u16x8){0, 0, 0, 0, 0, 0, 0, 0};
    }
    *(u16x8*)&sT[s * 64 + (d0 ^ ((s & 7) << 3))] = o;
  }
  __syncthreads();                     // BAR1

  // ---- qkv GEMM: wave w owns n = 32w..32w+31, one n-tile at a time ----
  const float QS = 0.25f;              // 1/sqrt(16)
  #pragma unroll
  for (int j = 0; j < 2; ++j) {
    int n = (2 * w + j) * 16 + lm;
    bf16x8 bfr0 = *(const bf16x8*)&wqkv_t[n * 64 + 8 * g];
    bf16x8 bfr1 = *(const bf16x8*)&wqkv_t[n * 64 + 32 + 8 * g];
    f32x4 acc[6];
    #pragma unroll
    for (int mt = 0; mt < 6; ++mt) acc[mt] = zf4;
    #pragma unroll
    for (int mt = 0; mt < 6; ++mt) {
      int m = mt * 16 + lm;
      bf16x8 a0 = *(const bf16x8*)&sT[m * 64 + ((8 * g) ^ ((m & 7) << 3))];
      bf16x8 a1 = *(const bf16x8*)&sT[m * 64 + ((32 + 8 * g) ^ ((m & 7) << 3))];
      acc[mt] = MFMA(a0, bfr0, acc[mt]);
      acc[mt] = MFMA(a1, bfr1, acc[mt]);
    }
    float bias = bqkv[n];
    #pragma unroll
    for (int mt = 0; mt < 6; ++mt)
      #pragma unroll
      for (int r = 0; r < 4; ++r) {
        int m = mt * 16 + 4 * g + r;
        float v = acc[mt][r] + bias;
        if (w < 2) {
          s_q[m * 64 + (n ^ ((m & 7) << 3))] = f2bf(v * QS);
        } else if (w < 4) {
          int d = n - 64;
          sK[m * 64 + (d ^ ((m & 7) << 3))] = f2bf(v);
        } else {
          int d = n - 128;
          s_v[d * 104 + m] = f2bf(v);
        }
      }
  }
  __syncthreads();                     // BAR2

  // ---- transposed attention: S^T = MFMA(K, Q); lane owns q = 16w+lm ----
  const int qrow = 16 * w + lm;
  const int sloLane = ((g & 1) << 5) + lm;
  const int shiLane = sloLane + 16;
  const unsigned psel = (g >= 2) ? 0x07060302u : 0x05040100u;
  f32x4 ctxn[4];
  #pragma unroll
  for (int h = 0; h < 4; ++h) {
    const int koff = h * 16 + (g & 1) * 8;    // K=16 padded to 32
    bf16x8 qb = *(const bf16x8*)&s_q[qrow * 64 + (koff ^ ((qrow & 7) << 3))];
    if (g >= 2) qb = z8;                      // zero B side for pad slots
    f32x4 sc[6];
    #pragma unroll
    for (int mt = 0; mt < 6; ++mt) {
      int kr = mt * 16 + lm;
      bf16x8 ka = *(const bf16x8*)&sK[kr * 64 + (koff ^ ((kr & 7) << 3))];
      sc[mt] = MFMA(ka, qb, zf4);             // D[kv=16mt+4g+r][q=16w+lm]
    }
    // lane-local softmax over kv (no max-sub: |scores| << 1), P unnormalized
    float ssum = 0.f;
    #pragma unroll
    for (int mt = 0; mt < 6; ++mt)
      #pragma unroll
      for (int r = 0; r < 4; ++r) {
        float x = __expf(sc[mt][r]);
        if (mt == 5 && (4 * g + r) >= 6) x = 0.f;   // mask kv 86..95
        sc[mt][r] = x;
        ssum += x;
      }
    ssum += __shfl_xor(ssum, 16);
    ssum += __shfl_xor(ssum, 32);
    float inv = 1.0f / ssum;
    // PV: ctx^T = MFMA(V^T, P^T); P^T B-frags via in-register exchange
    f32x4 ca = zf4;
    #pragma unroll
    for (int ks = 0; ks < 3; ++ks) {
      unsigned p0 = cvtpk(sc[2 * ks][0], sc[2 * ks + 1][0]);
      unsigned p1 = cvtpk(sc[2 * ks][1], sc[2 * ks + 1][1]);
      unsigned p2 = cvtpk(sc[2 * ks][2], sc[2 * ks + 1][2]);
      unsigned p3 = cvtpk(sc[2 * ks][3], sc[2 * ks + 1][3]);
      bf16x8 vb = xchg(p0, p1, p2, p3, sloLane, shiLane, psel);
      bf16x8 va = *(const bf16x8*)&s_v[(h * 16 + lm) * 104 + 32 * ks + 8 * g];
      ca = MFMA(va, vb, ca);
    }
    #pragma unroll
    for (int r = 0; r < 4; ++r) ctxn[h][r] = ca[r] * inv;
  }

  // ---- AO^T = MFMA(Wa^T, ctx^T): ctx B-frags via same exchange ----
  f32x4 ao[4];
  #pragma unroll
  for (int nt = 0; nt < 4; ++nt) ao[nt] = zf4;
  #pragma unroll
  for (int ks = 0; ks < 2; ++ks) {
    unsigned p0 = cvtpk(ctxn[2 * ks][0], ctxn[2 * ks + 1][0]);
    unsigned p1 = cvtpk(ctxn[2 * ks][1], ctxn[2 * ks + 1][1]);
    unsigned p2 = cvtpk(ctxn[2 * ks][2], ctxn[2 * ks + 1][2]);
    unsigned p3 = cvtpk(ctxn[2 * ks][3], ctxn[2 * ks + 1][3]);
    bf16x8 ab = xchg(p0, p1, p2, p3, sloLane, shiLane, psel);
    #pragma unroll
    for (int nt = 0; nt < 4; ++nt) {
      bf16x8 wf = *(const bf16x8*)&wa_t[(nt * 16 + lm) * 64 + 32 * ks + 8 * g];
      ao[nt] = MFMA(wf, ab, ao[nt]);
    }
  }
  __syncthreads();                     // BAR3: attn LDS reads done -> alias write
  #pragma unroll
  for (int nt = 0; nt < 4; ++nt)
    #pragma unroll
    for (int r = 0; r < 4; ++r) {
      int n = nt * 16 + 4 * g + r;
      sAO[n * 104 + 16 * w + lm] = f2bf(ao[nt][r] + ba[n]);
    }
  __syncthreads();                     // BAR4

  // ---- pooling: pools^T = MFMA(mask, AO) ----
  if (w < 4) {
    f32x4 pc = zf4;
    #pragma unroll
    for (int ks = 0; ks < 3; ++ks) {
      bf16x8 pa  = *(const bf16x8*)&pwm[lm * 96 + 32 * ks + 8 * g];
      bf16x8 ab2 = *(const bf16x8*)&sAO[(16 * w + lm) * 104 + 32 * ks + 8 * g];
      pc = MFMA(pa, ab2, pc);
    }
    if (g < 2) {
      #pragma unroll
      for (int r = 0; r < 4; ++r) {
        int p = 4 * g + r;               // 0..7
        sCC[p * 64 + 16 * w + lm] = f2bf(pc[r] * invc[p]);
      }
    }
  }
  __syncthreads();                     // BAR5

  // ---- final 512->128: out^T = MFMA(Wo^T, concat-broadcast) ----
  #pragma unroll
  for (int ti = 0; ti < 2; ++ti) {
    int t = w + 6 * ti;                // waves 0-5 -> tiles 0-5; waves 0,1 -> 6,7
    if (t < 8) {
      f32x4 fa = zf4;
      #pragma unroll 4
      for (int ks = 0; ks < 16; ++ks) {
        bf16x8 cb = *(const bf16x8*)&sCC[32 * ks + 8 * g];   // broadcast read
        bf16x8 wf = *(const bf16x8*)&wo_t[(t * 16 + lm) * 512 + 32 * ks + 8 * g];
        fa = MFMA(wf, cb, fa);
      }
      if (lm == 0) {
        #pragma unroll
        for (int r = 0; r < 4; ++r) {
          int n = t * 16 + 4 * g + r;
          out[(long)b * 128 + n] = fmaxf(fa[r] + bo[n], 0.f);
        }
      }
    }
  }
}

// ============================================================ launch
extern "C" void kernel_launch(void* const* d_in, const int* in_sizes, int n_in,
                              void* d_out, int out_size, void* d_ws, size_t ws_size,
                              hipStream_t stream) {
  const float* influence = (const float*)d_in[0];
  const float* cstat     = (const float*)d_in[1];
  const float* Wc        = (const float*)d_in[2];
  const float* bc        = (const float*)d_in[3];
  const float* Wqkv      = (const float*)d_in[4];
  const float* bqkv      = (const float*)d_in[5];
  const float* Wa        = (const float*)d_in[6];
  const float* ba        = (const float*)d_in[7];
  const float* Wo        = (const float*)d_in[8];
  const float* bo        = (const float*)d_in[9];
  float* out = (float*)d_out;
  char* ws = (char*)d_ws;

  float* sp              = (float*)(ws + OFF_SP);
  unsigned short* pwm    = (unsigned short*)(ws + OFF_PWM);
  float* invc            = (float*)(ws + OFF_INVC);
  unsigned short* wqkv_t = (unsigned short*)(ws + OFF_WQKV);
  unsigned short* wa_t   = (unsigned short*)(ws + OFF_WA);
  unsigned short* wo_t   = (unsigned short*)(ws + OFF_WO);

  hipLaunchKernelGGL(prologue, dim3(36), dim3(256), 0, stream,
                     cstat, Wc, bc, Wqkv, Wa, Wo, sp, pwm, invc, wqkv_t, wa_t, wo_t);
  hipLaunchKernelGGL(fused, dim3(B_TOT), dim3(384), 0, stream,
                     influence, Wc, sp, bqkv, ba, invc, bo,
                     wqkv_t, wa_t, pwm, wo_t, out);
}